// Round 1
// baseline (1319.984 us; speedup 1.0000x reference)
//
#include <hip/hip_runtime.h>
#include <math.h>

#define HH 64
#define WW 64
#define HW 4096
#define DIM 512
#define BATCH 8
#define HEADS 8
#define DH 64
#define BH 64    // BATCH*HEADS
#define KSEL 64  // 8x8 selected pixels

// ---------------- prep weights: wg = w*g, A[o]=sum(w*g), C[o]=sum(w*beta) ----
// grid 1536 blocks (3*512), 256 thr. widx 0: w_q/qs, 1: w_k/ctx, 2: w_v/ctx
__global__ void prep_weights(const float* __restrict__ w_q,
                             const float* __restrict__ w_kv,
                             const float* __restrict__ ctx_g, const float* __restrict__ ctx_b,
                             const float* __restrict__ qs_g, const float* __restrict__ qs_b,
                             float* __restrict__ wq_g, float* __restrict__ wk_g, float* __restrict__ wv_g,
                             float* __restrict__ Avec, float* __restrict__ Cvec)
{
    int blk = blockIdx.x;
    int widx = blk >> 9;
    int o = blk & 511;
    const float *src, *g, *beta;
    float* dst;
    if (widx == 0)      { src = w_q  + (size_t)o * DIM;        g = qs_g;  beta = qs_b;  dst = wq_g + (size_t)o * DIM; }
    else if (widx == 1) { src = w_kv + (size_t)o * DIM;        g = ctx_g; beta = ctx_b; dst = wk_g + (size_t)o * DIM; }
    else                { src = w_kv + (size_t)(512 + o) * DIM; g = ctx_g; beta = ctx_b; dst = wv_g + (size_t)o * DIM; }
    int tid = threadIdx.x;
    float a = 0.f, c = 0.f;
    for (int i = tid; i < DIM; i += 256) {
        float w = src[i];
        float wg = w * g[i];
        dst[i] = wg;
        a += wg;
        c += w * beta[i];
    }
    __shared__ float sa[256], sc[256];
    sa[tid] = a; sc[tid] = c;
    __syncthreads();
    for (int s = 128; s > 0; s >>= 1) {
        if (tid < s) { sa[tid] += sa[tid + s]; sc[tid] += sc[tid + s]; }
        __syncthreads();
    }
    if (tid == 0) { Avec[widx * 512 + o] = sa[0]; Cvec[widx * 512 + o] = sc[0]; }
}

// ---------------- per-pixel channel stats (mean, rstd) for ctx and qs -------
__global__ void chan_stats(const float* __restrict__ ctx, const float* __restrict__ qs,
                           float* __restrict__ ctx_m, float* __restrict__ ctx_r,
                           float* __restrict__ qs_m, float* __restrict__ qs_r)
{
    int t = blockIdx.x * blockDim.x + threadIdx.x;  // 2*32768 threads
    int which = t >> 15;
    int pix = t & 32767;
    const float* x = (which == 0 ? ctx : qs);
    int b = pix >> 12;
    int p = pix & 4095;
    const float* base = x + (size_t)b * DIM * HW + p;
    float s = 0.f, ss = 0.f;
    for (int i = 0; i < DIM; i++) {
        float v = base[(size_t)i * HW];
        s += v; ss = fmaf(v, v, ss);
    }
    float m = s * (1.0f / DIM);
    float var = ss * (1.0f / DIM) - m * m;
    float r = 1.0f / sqrtf(var + 1e-5f);
    if (which == 0) { ctx_m[pix] = m; ctx_r[pix] = r; }
    else            { qs_m[pix]  = m; qs_r[pix]  = r; }
}

// ---------------- fused tiled GEMM: Y[o,p] = f(sum_i W[o,i]*X[i,p]) ---------
// mode 0: Y = r[p]*(acc - m[p]*Arow[o]) + Crow[o]            (q / k projection)
// mode 1: Y = gamma*acc + (qsrc[o,p]-m[p])*r[p]*g[o] + beta[o] (out + residual)
#define BM 64
#define BN 64
#define BK 16
__global__ __launch_bounds__(256) void gemm512(
    const float* __restrict__ W, const float* __restrict__ X, float* __restrict__ Y,
    const float* __restrict__ mean, const float* __restrict__ rstd,
    const float* __restrict__ Arow, const float* __restrict__ Crow,
    const float* __restrict__ qsrc, const float* __restrict__ g, const float* __restrict__ beta,
    const float* __restrict__ gammaPtr, int mode)
{
    int b = blockIdx.z;
    int n0 = blockIdx.x * BN;
    int m0 = blockIdx.y * BM;
    const float* Xb = X + (size_t)b * DIM * HW;
    __shared__ float As[BK][BM];
    __shared__ float Bs[BK][BN];
    int tid = threadIdx.x;
    int tr = tid >> 4;   // 0..15
    int tc = tid & 15;   // 0..15
    float acc[4][4] = {};
    for (int k0 = 0; k0 < DIM; k0 += BK) {
#pragma unroll
        for (int l = 0; l < 4; l++) {
            int idx = l * 256 + tid;
            int r = idx >> 4, c = idx & 15;
            As[c][r] = W[(size_t)(m0 + r) * DIM + k0 + c];
        }
#pragma unroll
        for (int l = 0; l < 4; l++) {
            int idx = l * 256 + tid;
            int r = idx >> 6, c = idx & 63;
            Bs[r][c] = Xb[(size_t)(k0 + r) * HW + n0 + c];
        }
        __syncthreads();
#pragma unroll
        for (int kk = 0; kk < BK; kk++) {
            float av[4], bv[4];
#pragma unroll
            for (int i = 0; i < 4; i++) av[i] = As[kk][tr * 4 + i];
#pragma unroll
            for (int j = 0; j < 4; j++) bv[j] = Bs[kk][tc * 4 + j];
#pragma unroll
            for (int i = 0; i < 4; i++)
#pragma unroll
                for (int j = 0; j < 4; j++)
                    acc[i][j] = fmaf(av[i], bv[j], acc[i][j]);
        }
        __syncthreads();
    }
    float* Yb = Y + (size_t)b * DIM * HW;
    if (mode == 0) {
#pragma unroll
        for (int i = 0; i < 4; i++) {
            int o = m0 + tr * 4 + i;
            float Ao = Arow[o], Co = Crow[o];
#pragma unroll
            for (int j = 0; j < 4; j++) {
                int p = n0 + tc * 4 + j;
                int pix = b * HW + p;
                Yb[(size_t)o * HW + p] = rstd[pix] * (acc[i][j] - mean[pix] * Ao) + Co;
            }
        }
    } else {
        float gamma = gammaPtr[0];
        const float* qb = qsrc + (size_t)b * DIM * HW;
#pragma unroll
        for (int i = 0; i < 4; i++) {
            int o = m0 + tr * 4 + i;
            float go = g[o], bo = beta[o];
#pragma unroll
            for (int j = 0; j < 4; j++) {
                int p = n0 + tc * 4 + j;
                int pix = b * HW + p;
                float qn = (qb[(size_t)o * HW + p] - mean[pix]) * rstd[pix] * go + bo;
                Yb[(size_t)o * HW + p] = gamma * acc[i][j] + qn;
            }
        }
    }
}

// ---------------- in-place l2norm over DH for q and k (per bh, pixel) -------
__global__ void l2norm_inplace(float* __restrict__ q, float* __restrict__ k)
{
    int t = blockIdx.x * blockDim.x + threadIdx.x;  // 2*64*4096
    int which = t >> 18;
    int r = t & 262143;
    int bh = r >> 12;
    int p = r & 4095;
    float* x = (which == 0 ? q : k) + (size_t)bh * DH * HW + p;
    float vals[DH];
    float s = 0.f;
#pragma unroll
    for (int d = 0; d < DH; d++) {
        vals[d] = x[(size_t)d * HW];
        s = fmaf(vals[d], vals[d], s);
    }
    float inv = 1.0f / fmaxf(sqrtf(s), 1e-12f);
#pragma unroll
    for (int d = 0; d < DH; d++) x[(size_t)d * HW] = vals[d] * inv;
}

// ---------------- q_probe[row] = sum_p |q[row,p]|, row = bh*64+c ------------
__global__ void q_probe_kernel(const float* __restrict__ q, float* __restrict__ qp)
{
    int row = blockIdx.x;  // 4096
    const float* x = q + (size_t)row * HW;
    int tid = threadIdx.x;
    float s = 0.f;
    for (int i = tid; i < HW; i += 256) s += fabsf(x[i]);
    __shared__ float sm[256];
    sm[tid] = s;
    __syncthreads();
    for (int st = 128; st > 0; st >>= 1) {
        if (tid < st) sm[tid] += sm[tid + st];
        __syncthreads();
    }
    if (tid == 0) qp[row] = sm[0];
}

// ---------------- row/col |k| sums: k_height[row][h], k_width[row][w] -------
__global__ void k_sums(const float* __restrict__ k, float* __restrict__ khs, float* __restrict__ kws)
{
    int t = blockIdx.x * blockDim.x + threadIdx.x;  // 4096*64
    int row = t >> 6;
    int x = t & 63;
    const float* base = k + (size_t)row * HW;
    float sh = 0.f, sw = 0.f;
    for (int i = 0; i < 64; i++) {
        sh += fabsf(base[x * 64 + i]);
        sw += fabsf(base[i * 64 + x]);
    }
    khs[(size_t)row * 64 + x] = sh;
    kws[(size_t)row * 64 + x] = sw;
}

// ---------------- scores + top-8 (per bh); one wave per block ---------------
__global__ void score_topk(const float* __restrict__ qp, const float* __restrict__ khs,
                           const float* __restrict__ kws, int* __restrict__ idx_h, int* __restrict__ idx_w)
{
    int bh = blockIdx.x;
    int lane = threadIdx.x;  // 0..63
    float sr = 0.f, sc = 0.f;
    for (int c = 0; c < 64; c++) {
        float q = qp[bh * 64 + c];
        sr = fmaf(q, khs[(size_t)(bh * 64 + c) * 64 + lane], sr);
        sc = fmaf(q, kws[(size_t)(bh * 64 + c) * 64 + lane], sc);
    }
    float v = sr;
    for (int it = 0; it < 8; it++) {
        float bv = v; int bi = lane;
        for (int off = 1; off < 64; off <<= 1) {
            float ov = __shfl_xor(bv, off, 64);
            int oi = __shfl_xor(bi, off, 64);
            if (ov > bv || (ov == bv && oi < bi)) { bv = ov; bi = oi; }
        }
        if (lane == 0) idx_h[bh * 8 + it] = bi;
        if (lane == bi) v = -INFINITY;
    }
    v = sc;
    for (int it = 0; it < 8; it++) {
        float bv = v; int bi = lane;
        for (int off = 1; off < 64; off <<= 1) {
            float ov = __shfl_xor(bv, off, 64);
            int oi = __shfl_xor(bi, off, 64);
            if (ov > bv || (ov == bv && oi < bi)) { bv = ov; bi = oi; }
        }
        if (lane == 0) idx_w[bh * 8 + it] = bi;
        if (lane == bi) v = -INFINITY;
    }
}

// ---------------- gather k; compute v only at selected pixels ---------------
// grid 4096 (bh*64+j), 64 thr (d). v via fused-norm dot with wv_g.
__global__ void gather_kv(const float* __restrict__ k, const float* __restrict__ ctx,
                          const float* __restrict__ wv_g, const float* __restrict__ Av, const float* __restrict__ Cv,
                          const float* __restrict__ ctx_m, const float* __restrict__ ctx_r,
                          const int* __restrict__ idx_h, const int* __restrict__ idx_w,
                          float* __restrict__ kg, float* __restrict__ vg)
{
    int blk = blockIdx.x;
    int bh = blk >> 6;
    int j = blk & 63;
    int h = idx_h[bh * 8 + (j >> 3)];
    int w = idx_w[bh * 8 + (j & 7)];
    int p = h * 64 + w;
    int b = bh >> 3, head = bh & 7;
    int d = threadIdx.x;
    kg[(size_t)blk * 64 + d] = k[(size_t)(bh * 64 + d) * HW + p];
    int o = head * 64 + d;
    const float* wrow = wv_g + (size_t)o * DIM;
    const float* cb = ctx + (size_t)b * DIM * HW + p;
    float acc = 0.f;
    for (int i = 0; i < DIM; i++) acc = fmaf(wrow[i], cb[(size_t)i * HW], acc);
    int pix = b * HW + p;
    vg[(size_t)blk * 64 + d] = ctx_r[pix] * (acc - ctx_m[pix] * Av[o]) + Cv[o];
}

// ---------------- attention: 64 kv per bh, 4096 queries ---------------------
// scores in [-1,1] (unit q,k) -> softmax without max subtraction is safe.
__global__ __launch_bounds__(256) void attn_kernel(const float* __restrict__ q,
                                                   const float* __restrict__ kg, const float* __restrict__ vg,
                                                   float* __restrict__ aout)
{
    int bh = blockIdx.y;
    int tid = threadIdx.x;
    int p = blockIdx.x * 256 + tid;
    __shared__ float ks[KSEL][DH];
    __shared__ float vs[KSEL][DH];
    for (int l = 0; l < 16; l++) {
        int idx = l * 256 + tid;
        ks[idx >> 6][idx & 63] = kg[(size_t)bh * KSEL * DH + idx];
        vs[idx >> 6][idx & 63] = vg[(size_t)bh * KSEL * DH + idx];
    }
    __syncthreads();
    const float* qb = q + (size_t)bh * DH * HW + p;
    float qv[DH];
#pragma unroll
    for (int d = 0; d < DH; d++) qv[d] = qb[(size_t)d * HW];
    float out[DH] = {};
    float lsum = 0.f;
    for (int j = 0; j < KSEL; j++) {
        float s = 0.f;
#pragma unroll
        for (int d = 0; d < DH; d++) s = fmaf(qv[d], ks[j][d], s);
        float wj = __expf(s);
        lsum += wj;
#pragma unroll
        for (int d = 0; d < DH; d++) out[d] = fmaf(wj, vs[j][d], out[d]);
    }
    float inv = 1.0f / lsum;
    float* ob = aout + (size_t)bh * DH * HW + p;
#pragma unroll
    for (int d = 0; d < DH; d++) ob[(size_t)d * HW] = out[d] * inv;
}

extern "C" void kernel_launch(void* const* d_in, const int* in_sizes, int n_in,
                              void* d_out, int out_size, void* d_ws, size_t ws_size,
                              hipStream_t stream)
{
    (void)in_sizes; (void)n_in; (void)out_size; (void)ws_size;
    const float* ctx   = (const float*)d_in[0];
    const float* qs    = (const float*)d_in[1];
    const float* ctx_g = (const float*)d_in[2];
    const float* ctx_b = (const float*)d_in[3];
    const float* qs_g  = (const float*)d_in[4];
    const float* qs_b  = (const float*)d_in[5];
    const float* w_q   = (const float*)d_in[6];
    const float* w_kv  = (const float*)d_in[7];
    const float* w_out = (const float*)d_in[8];
    const float* gamma = (const float*)d_in[9];
    float* out = (float*)d_out;

    float* ws = (float*)d_ws;
    float* wq_g  = ws;                   // 262144
    float* wk_g  = wq_g + 262144;
    float* wv_g  = wk_g + 262144;
    float* Avec  = wv_g + 262144;        // 1536 (q,k,v)
    float* Cvec  = Avec + 1536;          // 1536
    float* ctx_m = Cvec + 1536;          // 32768
    float* ctx_r = ctx_m + 32768;
    float* qs_m  = ctx_r + 32768;
    float* qs_r  = qs_m + 32768;
    float* qp    = qs_r + 32768;         // 4096
    float* khs   = qp + 4096;            // 262144
    float* kws   = khs + 262144;         // 262144
    int*   idxh  = (int*)(kws + 262144); // 512
    int*   idxw  = idxh + 512;           // 512
    float* kg    = (float*)(idxw + 512); // 262144
    float* vg    = kg + 262144;          // 262144
    float* qbuf  = vg + 262144;          // 16777216
    float* kbuf  = qbuf + 16777216;      // 16777216 (reused as attn_out)

    prep_weights<<<1536, 256, 0, stream>>>(w_q, w_kv, ctx_g, ctx_b, qs_g, qs_b,
                                           wq_g, wk_g, wv_g, Avec, Cvec);
    chan_stats<<<256, 256, 0, stream>>>(ctx, qs, ctx_m, ctx_r, qs_m, qs_r);
    gemm512<<<dim3(64, 8, 8), 256, 0, stream>>>(wq_g, qs, qbuf, qs_m, qs_r,
                                                Avec, Cvec, nullptr, nullptr, nullptr, nullptr, 0);
    gemm512<<<dim3(64, 8, 8), 256, 0, stream>>>(wk_g, ctx, kbuf, ctx_m, ctx_r,
                                                Avec + 512, Cvec + 512, nullptr, nullptr, nullptr, nullptr, 0);
    l2norm_inplace<<<2048, 256, 0, stream>>>(qbuf, kbuf);
    q_probe_kernel<<<4096, 256, 0, stream>>>(qbuf, qp);
    k_sums<<<1024, 256, 0, stream>>>(kbuf, khs, kws);
    score_topk<<<64, 64, 0, stream>>>(qp, khs, kws, idxh, idxw);
    gather_kv<<<4096, 64, 0, stream>>>(kbuf, ctx, wv_g, Avec + 1024, Cvec + 1024,
                                       ctx_m, ctx_r, idxh, idxw, kg, vg);
    attn_kernel<<<dim3(16, 64), 256, 0, stream>>>(qbuf, kg, vg, kbuf);
    gemm512<<<dim3(64, 8, 8), 256, 0, stream>>>(w_out, kbuf, out, qs_m, qs_r,
                                                nullptr, nullptr, qs, qs_g, qs_b, gamma, 1);
}

// Round 2
// 581.587 us; speedup vs baseline: 2.2696x; 2.2696x over previous
//
#include <hip/hip_runtime.h>
#include <math.h>

#define HW 4096
#define DIM 512
#define BATCH 8

typedef __attribute__((ext_vector_type(8))) short short8;
typedef __attribute__((ext_vector_type(4))) float f32x4;

__device__ inline unsigned short f2bf(float f) {
    unsigned int u = __float_as_uint(f);
    u += 0x7fff + ((u >> 16) & 1);   // round-to-nearest-even
    return (unsigned short)(u >> 16);
}

// ---------- prep weights: bf16 w*g for q/k, fp32 w*g for v, bf16 w_out ------
// grid 2048 (4*512), 256 thr. widx 0:q 1:k 2:v 3:out
__global__ void prep_weights(const float* __restrict__ w_q, const float* __restrict__ w_kv,
                             const float* __restrict__ w_out,
                             const float* __restrict__ ctx_g, const float* __restrict__ ctx_b,
                             const float* __restrict__ qs_g, const float* __restrict__ qs_b,
                             unsigned short* __restrict__ wq_b, unsigned short* __restrict__ wk_b,
                             unsigned short* __restrict__ wo_b, float* __restrict__ wv_g,
                             float* __restrict__ Avec, float* __restrict__ Cvec)
{
    int blk = blockIdx.x;
    int widx = blk >> 9;
    int o = blk & 511;
    int tid = threadIdx.x;
    const float *src, *g = nullptr, *beta = nullptr;
    if (widx == 0)      { src = w_q  + (size_t)o * DIM; g = qs_g;  beta = qs_b; }
    else if (widx == 1) { src = w_kv + (size_t)o * DIM; g = ctx_g; beta = ctx_b; }
    else if (widx == 2) { src = w_kv + (size_t)(512 + o) * DIM; g = ctx_g; beta = ctx_b; }
    else                { src = w_out + (size_t)o * DIM; }
    float a = 0.f, c = 0.f;
    for (int i = tid; i < DIM; i += 256) {
        float w = src[i];
        if (widx == 3) { wo_b[(size_t)o * DIM + i] = f2bf(w); continue; }
        float wg = w * g[i];
        if (widx == 0)      wq_b[(size_t)o * DIM + i] = f2bf(wg);
        else if (widx == 1) wk_b[(size_t)o * DIM + i] = f2bf(wg);
        else                wv_g[(size_t)o * DIM + i] = wg;
        a += wg; c += w * beta[i];
    }
    if (widx == 3) return;  // uniform across block
    __shared__ float sa[256], sc[256];
    sa[tid] = a; sc[tid] = c;
    __syncthreads();
    for (int s = 128; s > 0; s >>= 1) {
        if (tid < s) { sa[tid] += sa[tid + s]; sc[tid] += sc[tid + s]; }
        __syncthreads();
    }
    if (tid == 0) { Avec[widx * 512 + o] = sa[0]; Cvec[widx * 512 + o] = sc[0]; }
}

// ---------- fused: fp32->bf16 transpose (X[i][p] -> Xt[p][i]) + chan stats --
// grid (HW/64, B, 2). block 256: 64 pixels x 4 i-quarters.
__global__ __launch_bounds__(256) void conv_stats(
    const float* __restrict__ ctx, const float* __restrict__ qs,
    unsigned short* __restrict__ ctx_t, unsigned short* __restrict__ qs_t,
    float* __restrict__ ctx_m, float* __restrict__ ctx_r,
    float* __restrict__ qs_m, float* __restrict__ qs_r)
{
    int which = blockIdx.z;
    int b = blockIdx.y;
    int p0 = blockIdx.x * 64;
    const float* X = (which ? qs : ctx) + (size_t)b * DIM * HW;
    unsigned short* Xt = (which ? qs_t : ctx_t) + (size_t)b * HW * DIM;
    int tid = threadIdx.x;
    int p = p0 + (tid & 63);
    int q4 = tid >> 6;
    const float* col = X + p;
    unsigned short* orow = Xt + (size_t)p * DIM;
    float s = 0.f, ss = 0.f;
    for (int i0 = q4 * 128; i0 < q4 * 128 + 128; i0 += 8) {
        float v[8];
#pragma unroll
        for (int j = 0; j < 8; j++) {
            v[j] = col[(size_t)(i0 + j) * HW];
            s += v[j]; ss = fmaf(v[j], v[j], ss);
        }
        uint4 pk;
        pk.x = (unsigned)f2bf(v[0]) | ((unsigned)f2bf(v[1]) << 16);
        pk.y = (unsigned)f2bf(v[2]) | ((unsigned)f2bf(v[3]) << 16);
        pk.z = (unsigned)f2bf(v[4]) | ((unsigned)f2bf(v[5]) << 16);
        pk.w = (unsigned)f2bf(v[6]) | ((unsigned)f2bf(v[7]) << 16);
        *(uint4*)(orow + i0) = pk;
    }
    __shared__ float sbuf[256], ssbuf[256];
    sbuf[tid] = s; ssbuf[tid] = ss;
    __syncthreads();
    if (tid < 64) {
        float st  = sbuf[tid] + sbuf[tid + 64] + sbuf[tid + 128] + sbuf[tid + 192];
        float sst = ssbuf[tid] + ssbuf[tid + 64] + ssbuf[tid + 128] + ssbuf[tid + 192];
        float m = st * (1.0f / DIM);
        float var = sst * (1.0f / DIM) - m * m;
        float r = 1.0f / sqrtf(var + 1e-5f);
        int pix = b * HW + p0 + tid;
        if (which == 0) { ctx_m[pix] = m; ctx_r[pix] = r; }
        else            { qs_m[pix]  = m; qs_r[pix]  = r; }
    }
}

// ---------- bf16 MFMA GEMM, 128x128 tile, fused LN-fold + (mode0) l2norm ----
// W: 512x512 bf16 K-contig. Xt: per batch 4096x512 bf16 K-contig.
// mode 0: Y[m][n] = l2norm_over_head( rstd*(acc - mean*A[m]) + C[m] )  fp32 [o][p]
// mode 1: Y[m][n] = gamma*acc + (qsrc[m][n]-mean)*rstd*g[m] + beta[m]
__global__ __launch_bounds__(256) void gemm_mfma(
    const unsigned short* __restrict__ Wb, const unsigned short* __restrict__ Xt,
    float* __restrict__ Y,
    const float* __restrict__ mean, const float* __restrict__ rstd,
    const float* __restrict__ Arow, const float* __restrict__ Crow,
    const float* __restrict__ qsrc, const float* __restrict__ g,
    const float* __restrict__ beta, const float* __restrict__ gammaPtr, int mode)
{
    int b = blockIdx.z;
    int n0 = blockIdx.x * 128;
    int m0 = blockIdx.y * 128;
    const unsigned short* Xb = Xt + (size_t)b * HW * DIM;
    __shared__ uint4 AsBuf[512];   // 128 rows (m) x 32 k bf16
    __shared__ uint4 BsBuf[512];   // 128 rows (n) x 32 k bf16
    unsigned short* As = (unsigned short*)AsBuf;
    unsigned short* Bs = (unsigned short*)BsBuf;
    int tid = threadIdx.x;
    int lane = tid & 63;
    int wave = tid >> 6;
    int wm = (wave >> 1) * 64;   // wave's m offset (one head for mode 0)
    int wn = (wave & 1) * 64;
    int quad = lane >> 4;
    int l16 = lane & 15;

    int r0 = tid >> 2, c0 = (tid & 3) * 8;
    const uint4* gA0 = (const uint4*)(Wb + (size_t)(m0 + r0) * DIM + c0);
    const uint4* gA1 = (const uint4*)(Wb + (size_t)(m0 + 64 + r0) * DIM + c0);
    const uint4* gB0 = (const uint4*)(Xb + (size_t)(n0 + r0) * DIM + c0);
    const uint4* gB1 = (const uint4*)(Xb + (size_t)(n0 + 64 + r0) * DIM + c0);

    f32x4 acc[4][4];
#pragma unroll
    for (int i = 0; i < 4; i++)
#pragma unroll
        for (int j = 0; j < 4; j++) acc[i][j] = (f32x4){0.f, 0.f, 0.f, 0.f};

    uint4 ra0 = gA0[0], ra1 = gA1[0], rb0 = gB0[0], rb1 = gB1[0];
    for (int kt = 0; kt < 16; kt++) {
        ((uint4*)As)[tid] = ra0;
        ((uint4*)As)[tid + 256] = ra1;
        ((uint4*)Bs)[tid] = rb0;
        ((uint4*)Bs)[tid + 256] = rb1;
        __syncthreads();
        if (kt < 15) {  // register prefetch of next K-tile (k advance = 32 bf16 = 4 uint4)
            ra0 = gA0[(kt + 1) * 4]; ra1 = gA1[(kt + 1) * 4];
            rb0 = gB0[(kt + 1) * 4]; rb1 = gB1[(kt + 1) * 4];
        }
        short8 af[4], bfr[4];
#pragma unroll
        for (int i = 0; i < 4; i++)
            af[i] = *(const short8*)(As + (wm + i * 16 + l16) * 32 + quad * 8);
#pragma unroll
        for (int j = 0; j < 4; j++)
            bfr[j] = *(const short8*)(Bs + (wn + j * 16 + l16) * 32 + quad * 8);
#pragma unroll
        for (int i = 0; i < 4; i++)
#pragma unroll
            for (int j = 0; j < 4; j++)
                acc[i][j] = __builtin_amdgcn_mfma_f32_16x16x32_bf16(af[i], bfr[j], acc[i][j], 0, 0, 0);
        __syncthreads();
    }

    float* Yb = Y + (size_t)b * DIM * HW;
#pragma unroll
    for (int j = 0; j < 4; j++) {
        int n = n0 + wn + j * 16 + l16;
        int pix = b * HW + n;
        float mn = mean[pix], rs = rstd[pix];
        if (mode == 0) {
            float y[4][4];
            float s2 = 0.f;
#pragma unroll
            for (int i = 0; i < 4; i++) {
                int mb = m0 + wm + i * 16 + quad * 4;
#pragma unroll
                for (int r = 0; r < 4; r++) {
                    float v = rs * (acc[i][j][r] - mn * Arow[mb + r]) + Crow[mb + r];
                    y[i][r] = v;
                    s2 = fmaf(v, v, s2);
                }
            }
            // head norm: sum over the wave's 64 m rows = reduce across quads
            s2 += __shfl_xor(s2, 16);
            s2 += __shfl_xor(s2, 32);
            float inv = 1.0f / fmaxf(sqrtf(s2), 1e-12f);
#pragma unroll
            for (int i = 0; i < 4; i++) {
                int mb = m0 + wm + i * 16 + quad * 4;
#pragma unroll
                for (int r = 0; r < 4; r++)
                    Yb[(size_t)(mb + r) * HW + n] = y[i][r] * inv;
            }
        } else {
            float gamma = gammaPtr[0];
            const float* qb = qsrc + (size_t)b * DIM * HW;
#pragma unroll
            for (int i = 0; i < 4; i++) {
                int mb = m0 + wm + i * 16 + quad * 4;
#pragma unroll
                for (int r = 0; r < 4; r++) {
                    int m = mb + r;
                    float qn = (qb[(size_t)m * HW + n] - mn) * rs * g[m] + beta[m];
                    Yb[(size_t)m * HW + n] = gamma * acc[i][j][r] + qn;
                }
            }
        }
    }
}

// ---------- q_probe[row] = sum_p |q[row,p]| --------------------------------
__global__ void q_probe_kernel(const float* __restrict__ q, float* __restrict__ qp)
{
    int row = blockIdx.x;  // 4096
    const float* x = q + (size_t)row * HW;
    int tid = threadIdx.x;
    float s = 0.f;
    for (int i = tid; i < HW; i += 256) s += fabsf(x[i]);
    __shared__ float sm[256];
    sm[tid] = s;
    __syncthreads();
    for (int st = 128; st > 0; st >>= 1) {
        if (tid < st) sm[tid] += sm[tid + st];
        __syncthreads();
    }
    if (tid == 0) qp[row] = sm[0];
}

// ---------- row/col |k| sums ------------------------------------------------
__global__ void k_sums(const float* __restrict__ k, float* __restrict__ khs, float* __restrict__ kws)
{
    int t = blockIdx.x * blockDim.x + threadIdx.x;  // 4096*64
    int row = t >> 6;
    int x = t & 63;
    const float* base = k + (size_t)row * HW;
    float sh = 0.f, sw = 0.f;
    for (int i = 0; i < 64; i++) {
        sh += fabsf(base[x * 64 + i]);
        sw += fabsf(base[i * 64 + x]);
    }
    khs[(size_t)row * 64 + x] = sh;
    kws[(size_t)row * 64 + x] = sw;
}

// ---------- scores + top-8 per bh ------------------------------------------
__global__ void score_topk(const float* __restrict__ qp, const float* __restrict__ khs,
                           const float* __restrict__ kws, int* __restrict__ idx_h, int* __restrict__ idx_w)
{
    int bh = blockIdx.x;
    int lane = threadIdx.x;
    float sr = 0.f, sc = 0.f;
    for (int c = 0; c < 64; c++) {
        float q = qp[bh * 64 + c];
        sr = fmaf(q, khs[(size_t)(bh * 64 + c) * 64 + lane], sr);
        sc = fmaf(q, kws[(size_t)(bh * 64 + c) * 64 + lane], sc);
    }
    float v = sr;
    for (int it = 0; it < 8; it++) {
        float bv = v; int bi = lane;
        for (int off = 1; off < 64; off <<= 1) {
            float ov = __shfl_xor(bv, off, 64);
            int oi = __shfl_xor(bi, off, 64);
            if (ov > bv || (ov == bv && oi < bi)) { bv = ov; bi = oi; }
        }
        if (lane == 0) idx_h[bh * 8 + it] = bi;
        if (lane == bi) v = -INFINITY;
    }
    v = sc;
    for (int it = 0; it < 8; it++) {
        float bv = v; int bi = lane;
        for (int off = 1; off < 64; off <<= 1) {
            float ov = __shfl_xor(bv, off, 64);
            int oi = __shfl_xor(bi, off, 64);
            if (ov > bv || (ov == bv && oi < bi)) { bv = ov; bi = oi; }
        }
        if (lane == 0) idx_w[bh * 8 + it] = bi;
        if (lane == bi) v = -INFINITY;
    }
}

// ---------- gather k (already normalized); compute v at selected pixels ----
__global__ void gather_kv(const float* __restrict__ k, const float* __restrict__ ctx,
                          const float* __restrict__ wv_g, const float* __restrict__ Av, const float* __restrict__ Cv,
                          const float* __restrict__ ctx_m, const float* __restrict__ ctx_r,
                          const int* __restrict__ idx_h, const int* __restrict__ idx_w,
                          float* __restrict__ kg, float* __restrict__ vg)
{
    int blk = blockIdx.x;
    int bh = blk >> 6;
    int j = blk & 63;
    int h = idx_h[bh * 8 + (j >> 3)];
    int w = idx_w[bh * 8 + (j & 7)];
    int p = h * 64 + w;
    int b = bh >> 3, head = bh & 7;
    int d = threadIdx.x;
    kg[(size_t)blk * 64 + d] = k[(size_t)(bh * 64 + d) * HW + p];
    int o = head * 64 + d;
    const float* wrow = wv_g + (size_t)o * DIM;
    const float* cb = ctx + (size_t)b * DIM * HW + p;
    float acc = 0.f;
    for (int i = 0; i < DIM; i++) acc = fmaf(wrow[i], cb[(size_t)i * HW], acc);
    int pix = b * HW + p;
    vg[(size_t)blk * 64 + d] = ctx_r[pix] * (acc - ctx_m[pix] * Av[o]) + Cv[o];
}

// ---------- attention; writes bf16 transposed (out-GEMM B operand) ----------
__global__ __launch_bounds__(256) void attn_kernel(const float* __restrict__ q,
                                                   const float* __restrict__ kg, const float* __restrict__ vg,
                                                   unsigned short* __restrict__ abuf)
{
    int bh = blockIdx.y;
    int tid = threadIdx.x;
    int p = blockIdx.x * 256 + tid;
    __shared__ float ks[64][64];
    __shared__ float vs[64][64];
    for (int l = 0; l < 16; l++) {
        int idx = l * 256 + tid;
        ks[idx >> 6][idx & 63] = kg[(size_t)bh * 4096 + idx];
        vs[idx >> 6][idx & 63] = vg[(size_t)bh * 4096 + idx];
    }
    __syncthreads();
    const float* qb = q + (size_t)bh * 64 * HW + p;
    float qv[64];
#pragma unroll
    for (int d = 0; d < 64; d++) qv[d] = qb[(size_t)d * HW];
    float out[64] = {};
    float lsum = 0.f;
    for (int j = 0; j < 64; j++) {
        float s = 0.f;
#pragma unroll
        for (int d = 0; d < 64; d++) s = fmaf(qv[d], ks[j][d], s);
        float wj = __expf(s);  // scores in [-1,1]: safe without max-sub
        lsum += wj;
#pragma unroll
        for (int d = 0; d < 64; d++) out[d] = fmaf(wj, vs[j][d], out[d]);
    }
    float inv = 1.0f / lsum;
    int b = bh >> 3, head = bh & 7;
    uint4* ob = (uint4*)(abuf + (size_t)(b * HW + p) * DIM + head * 64);
#pragma unroll
    for (int c = 0; c < 8; c++) {
        uint4 pk;
        pk.x = (unsigned)f2bf(out[c*8+0]*inv) | ((unsigned)f2bf(out[c*8+1]*inv) << 16);
        pk.y = (unsigned)f2bf(out[c*8+2]*inv) | ((unsigned)f2bf(out[c*8+3]*inv) << 16);
        pk.z = (unsigned)f2bf(out[c*8+4]*inv) | ((unsigned)f2bf(out[c*8+5]*inv) << 16);
        pk.w = (unsigned)f2bf(out[c*8+6]*inv) | ((unsigned)f2bf(out[c*8+7]*inv) << 16);
        ob[c] = pk;
    }
}

extern "C" void kernel_launch(void* const* d_in, const int* in_sizes, int n_in,
                              void* d_out, int out_size, void* d_ws, size_t ws_size,
                              hipStream_t stream)
{
    (void)in_sizes; (void)n_in; (void)out_size; (void)ws_size;
    const float* ctx   = (const float*)d_in[0];
    const float* qs    = (const float*)d_in[1];
    const float* ctx_g = (const float*)d_in[2];
    const float* ctx_b = (const float*)d_in[3];
    const float* qs_g  = (const float*)d_in[4];
    const float* qs_b  = (const float*)d_in[5];
    const float* w_q   = (const float*)d_in[6];
    const float* w_kv  = (const float*)d_in[7];
    const float* w_out = (const float*)d_in[8];
    const float* gamma = (const float*)d_in[9];
    float* out = (float*)d_out;

    char* base = (char*)d_ws;
    // [0,32M): ctx_t (bf16), later aliased by abuf (attn out, bf16)
    // [32M,96M): qs_t (bf16, first 32M) then kbuf fp32 overwrites (qs_t dead)
    // [96M,160M): qbuf fp32
    // [160M,...): small buffers
    unsigned short* ctx_t = (unsigned short*)base;
    unsigned short* qs_t  = (unsigned short*)(base + ((size_t)32 << 20));
    float* kbuf = (float*)(base + ((size_t)32 << 20));
    float* qbuf = (float*)(base + ((size_t)96 << 20));
    unsigned short* abuf = ctx_t;
    char* tail = base + ((size_t)160 << 20);
    unsigned short* wq_b = (unsigned short*)tail;           // 262144 us
    unsigned short* wk_b = wq_b + 262144;
    unsigned short* wo_b = wk_b + 262144;
    float* wv_g  = (float*)(wo_b + 262144);                 // 262144 f
    float* Avec  = wv_g + 262144;                           // 1536
    float* Cvec  = Avec + 1536;
    float* ctx_m = Cvec + 1536;                             // 32768 each
    float* ctx_r = ctx_m + 32768;
    float* qs_m  = ctx_r + 32768;
    float* qs_r  = qs_m + 32768;
    float* qp    = qs_r + 32768;                            // 4096
    float* khs   = qp + 4096;                               // 262144
    float* kws   = khs + 262144;                            // 262144
    int*   idxh  = (int*)(kws + 262144);                    // 512
    int*   idxw  = idxh + 512;
    float* kg    = (float*)(idxw + 512);                    // 262144
    float* vg    = kg + 262144;                             // 262144

    prep_weights<<<2048, 256, 0, stream>>>(w_q, w_kv, w_out, ctx_g, ctx_b, qs_g, qs_b,
                                           wq_b, wk_b, wo_b, wv_g, Avec, Cvec);
    conv_stats<<<dim3(64, 8, 2), 256, 0, stream>>>(ctx, qs, ctx_t, qs_t,
                                                   ctx_m, ctx_r, qs_m, qs_r);
    gemm_mfma<<<dim3(32, 4, 8), 256, 0, stream>>>(wq_b, qs_t, qbuf, qs_m, qs_r,
                                                  Avec, Cvec, nullptr, nullptr, nullptr, nullptr, 0);
    gemm_mfma<<<dim3(32, 4, 8), 256, 0, stream>>>(wk_b, ctx_t, kbuf, ctx_m, ctx_r,
                                                  Avec + 512, Cvec + 512, nullptr, nullptr, nullptr, nullptr, 0);
    q_probe_kernel<<<4096, 256, 0, stream>>>(qbuf, qp);
    k_sums<<<1024, 256, 0, stream>>>(kbuf, khs, kws);
    score_topk<<<64, 64, 0, stream>>>(qp, khs, kws, idxh, idxw);
    gather_kv<<<4096, 64, 0, stream>>>(kbuf, ctx, wv_g, Avec + 1024, Cvec + 1024,
                                       ctx_m, ctx_r, idxh, idxw, kg, vg);
    attn_kernel<<<dim3(16, 64), 256, 0, stream>>>(qbuf, kg, vg, abuf);
    gemm_mfma<<<dim3(32, 4, 8), 256, 0, stream>>>(wo_b, abuf, out, qs_m, qs_r,
                                                  nullptr, nullptr, qs, qs_g, qs_b, gamma, 1);
}

// Round 3
// 481.151 us; speedup vs baseline: 2.7434x; 1.2087x over previous
//
#include <hip/hip_runtime.h>
#include <math.h>

#define HW 4096
#define DIM 512

typedef __attribute__((ext_vector_type(8))) short short8;
typedef __attribute__((ext_vector_type(4))) float f32x4;

__device__ inline unsigned short f2bf(float f) {
    unsigned int u = __float_as_uint(f);
    u += 0x7fff + ((u >> 16) & 1);   // round-to-nearest-even
    return (unsigned short)(u >> 16);
}
__device__ inline float bf2f(unsigned short h) {
    return __uint_as_float(((unsigned int)h) << 16);
}
__device__ inline unsigned pack2(float a, float b) {
    return (unsigned)f2bf(a) | ((unsigned)f2bf(b) << 16);
}

// ---------- prep weights: bf16 w*g for q/k, fp32 w*g for v, bf16 w_out ------
__global__ void prep_weights(const float* __restrict__ w_q, const float* __restrict__ w_kv,
                             const float* __restrict__ w_out,
                             const float* __restrict__ ctx_g, const float* __restrict__ ctx_b,
                             const float* __restrict__ qs_g, const float* __restrict__ qs_b,
                             unsigned short* __restrict__ wq_b, unsigned short* __restrict__ wk_b,
                             unsigned short* __restrict__ wo_b, float* __restrict__ wv_g,
                             float* __restrict__ Avec, float* __restrict__ Cvec)
{
    int blk = blockIdx.x;
    int widx = blk >> 9;
    int o = blk & 511;
    int tid = threadIdx.x;
    const float *src, *g = nullptr, *beta = nullptr;
    if (widx == 0)      { src = w_q  + (size_t)o * DIM; g = qs_g;  beta = qs_b; }
    else if (widx == 1) { src = w_kv + (size_t)o * DIM; g = ctx_g; beta = ctx_b; }
    else if (widx == 2) { src = w_kv + (size_t)(512 + o) * DIM; g = ctx_g; beta = ctx_b; }
    else                { src = w_out + (size_t)o * DIM; }
    float a = 0.f, c = 0.f;
    for (int i = tid; i < DIM; i += 256) {
        float w = src[i];
        if (widx == 3) { wo_b[(size_t)o * DIM + i] = f2bf(w); continue; }
        float wg = w * g[i];
        if (widx == 0)      wq_b[(size_t)o * DIM + i] = f2bf(wg);
        else if (widx == 1) wk_b[(size_t)o * DIM + i] = f2bf(wg);
        else                wv_g[(size_t)o * DIM + i] = wg;
        a += wg; c += w * beta[i];
    }
    if (widx == 3) return;  // uniform across block
    __shared__ float sa[256], sc[256];
    sa[tid] = a; sc[tid] = c;
    __syncthreads();
    for (int s = 128; s > 0; s >>= 1) {
        if (tid < s) { sa[tid] += sa[tid + s]; sc[tid] += sc[tid + s]; }
        __syncthreads();
    }
    if (tid == 0) { Avec[widx * 512 + o] = sa[0]; Cvec[widx * 512 + o] = sc[0]; }
}

// ---------- fused: fp32->bf16 transpose (X[i][p] -> Xt[p][i]) + chan stats --
__global__ __launch_bounds__(256) void conv_stats(
    const float* __restrict__ ctx, const float* __restrict__ qs,
    unsigned short* __restrict__ ctx_t, unsigned short* __restrict__ qs_t,
    float* __restrict__ ctx_m, float* __restrict__ ctx_r,
    float* __restrict__ qs_m, float* __restrict__ qs_r)
{
    int which = blockIdx.z;
    int b = blockIdx.y;
    int p0 = blockIdx.x * 64;
    const float* X = (which ? qs : ctx) + (size_t)b * DIM * HW;
    unsigned short* Xt = (which ? qs_t : ctx_t) + (size_t)b * HW * DIM;
    int tid = threadIdx.x;
    int p = p0 + (tid & 63);
    int q4 = tid >> 6;
    const float* col = X + p;
    unsigned short* orow = Xt + (size_t)p * DIM;
    float s = 0.f, ss = 0.f;
    for (int i0 = q4 * 128; i0 < q4 * 128 + 128; i0 += 8) {
        float v[8];
#pragma unroll
        for (int j = 0; j < 8; j++) {
            v[j] = col[(size_t)(i0 + j) * HW];
            s += v[j]; ss = fmaf(v[j], v[j], ss);
        }
        uint4 pk;
        pk.x = pack2(v[0], v[1]);
        pk.y = pack2(v[2], v[3]);
        pk.z = pack2(v[4], v[5]);
        pk.w = pack2(v[6], v[7]);
        *(uint4*)(orow + i0) = pk;
    }
    __shared__ float sbuf[256], ssbuf[256];
    sbuf[tid] = s; ssbuf[tid] = ss;
    __syncthreads();
    if (tid < 64) {
        float st  = sbuf[tid] + sbuf[tid + 64] + sbuf[tid + 128] + sbuf[tid + 192];
        float sst = ssbuf[tid] + ssbuf[tid + 64] + ssbuf[tid + 128] + ssbuf[tid + 192];
        float m = st * (1.0f / DIM);
        float var = sst * (1.0f / DIM) - m * m;
        float r = 1.0f / sqrtf(var + 1e-5f);
        int pix = b * HW + p0 + tid;
        if (which == 0) { ctx_m[pix] = m; ctx_r[pix] = r; }
        else            { qs_m[pix]  = m; qs_r[pix]  = r; }
    }
}

// ---------- bf16 MFMA GEMM, 128x128 tile -----------------------------------
// MODE 0: q proj -> l2norm -> bf16 [p][512]; |.| row sums atomically into probe[b*512+m]
// MODE 1: k proj -> l2norm -> bf16 [p][512]; khs atomics into probe[(b*512+m)*64+h]
// MODE 2: out GEMM -> fp32 [m][p] with gamma*acc + LN(qsrc) residual
template<int MODE>
__global__ __launch_bounds__(256) void gemm_mfma(
    const unsigned short* __restrict__ Wb, const unsigned short* __restrict__ Xt,
    float* __restrict__ Y, unsigned short* __restrict__ Ybf,
    const float* __restrict__ mean, const float* __restrict__ rstd,
    const float* __restrict__ Arow, const float* __restrict__ Crow,
    float* __restrict__ probe,
    const float* __restrict__ qsrc, const float* __restrict__ g,
    const float* __restrict__ beta, const float* __restrict__ gammaPtr)
{
    int b = blockIdx.z;
    int n0 = blockIdx.x * 128;
    int m0 = blockIdx.y * 128;
    const unsigned short* Xb = Xt + (size_t)b * HW * DIM;
    __shared__ uint4 AsBuf[512];   // 128 rows (m) x 32 k bf16
    __shared__ uint4 BsBuf[512];   // 128 rows (n) x 32 k bf16
    unsigned short* As = (unsigned short*)AsBuf;
    unsigned short* Bs = (unsigned short*)BsBuf;
    int tid = threadIdx.x;
    int lane = tid & 63;
    int wave = tid >> 6;
    int wm = (wave >> 1) * 64;
    int wn = (wave & 1) * 64;
    int quad = lane >> 4;
    int l16 = lane & 15;

    int r0 = tid >> 2, c0 = (tid & 3) * 8;
    const uint4* gA0 = (const uint4*)(Wb + (size_t)(m0 + r0) * DIM + c0);
    const uint4* gA1 = (const uint4*)(Wb + (size_t)(m0 + 64 + r0) * DIM + c0);
    const uint4* gB0 = (const uint4*)(Xb + (size_t)(n0 + r0) * DIM + c0);
    const uint4* gB1 = (const uint4*)(Xb + (size_t)(n0 + 64 + r0) * DIM + c0);

    f32x4 acc[4][4];
#pragma unroll
    for (int i = 0; i < 4; i++)
#pragma unroll
        for (int j = 0; j < 4; j++) acc[i][j] = (f32x4){0.f, 0.f, 0.f, 0.f};

    uint4 ra0 = gA0[0], ra1 = gA1[0], rb0 = gB0[0], rb1 = gB1[0];
    for (int kt = 0; kt < 16; kt++) {
        ((uint4*)As)[tid] = ra0;
        ((uint4*)As)[tid + 256] = ra1;
        ((uint4*)Bs)[tid] = rb0;
        ((uint4*)Bs)[tid + 256] = rb1;
        __syncthreads();
        if (kt < 15) {
            ra0 = gA0[(kt + 1) * 4]; ra1 = gA1[(kt + 1) * 4];
            rb0 = gB0[(kt + 1) * 4]; rb1 = gB1[(kt + 1) * 4];
        }
        short8 af[4], bfr[4];
#pragma unroll
        for (int i = 0; i < 4; i++)
            af[i] = *(const short8*)(As + (wm + i * 16 + l16) * 32 + quad * 8);
#pragma unroll
        for (int j = 0; j < 4; j++)
            bfr[j] = *(const short8*)(Bs + (wn + j * 16 + l16) * 32 + quad * 8);
#pragma unroll
        for (int i = 0; i < 4; i++)
#pragma unroll
            for (int j = 0; j < 4; j++)
                acc[i][j] = __builtin_amdgcn_mfma_f32_16x16x32_bf16(af[i], bfr[j], acc[i][j], 0, 0, 0);
        __syncthreads();
    }

    if (MODE < 2) {
        float pa[4][4] = {};
#pragma unroll
        for (int j = 0; j < 4; j++) {
            int n = n0 + wn + j * 16 + l16;
            int pix = b * HW + n;
            float mn = mean[pix], rs = rstd[pix];
            float y[4][4];
            float s2 = 0.f;
#pragma unroll
            for (int i = 0; i < 4; i++) {
                int mb = m0 + wm + i * 16 + quad * 4;
#pragma unroll
                for (int r = 0; r < 4; r++) {
                    float v = rs * (acc[i][j][r] - mn * Arow[mb + r]) + Crow[mb + r];
                    y[i][r] = v;
                    s2 = fmaf(v, v, s2);
                }
            }
            // head l2-norm: wave spans exactly one 64-channel head in m
            s2 += __shfl_xor(s2, 16, 64);
            s2 += __shfl_xor(s2, 32, 64);
            float inv = 1.0f / fmaxf(sqrtf(s2), 1e-12f);
            unsigned short* orow = Ybf + (size_t)(b * HW + n) * 512 + m0 + wm + quad * 4;
#pragma unroll
            for (int i = 0; i < 4; i++) {
                float v0 = y[i][0] * inv, v1 = y[i][1] * inv;
                float v2 = y[i][2] * inv, v3 = y[i][3] * inv;
                uint2 pk; pk.x = pack2(v0, v1); pk.y = pack2(v2, v3);
                *(uint2*)(orow + i * 16) = pk;
                pa[i][0] += fabsf(v0); pa[i][1] += fabsf(v1);
                pa[i][2] += fabsf(v2); pa[i][3] += fabsf(v3);
            }
        }
#pragma unroll
        for (int i = 0; i < 4; i++)
#pragma unroll
            for (int r = 0; r < 4; r++) {
                float v = pa[i][r];
                v += __shfl_xor(v, 1, 64);
                v += __shfl_xor(v, 2, 64);
                v += __shfl_xor(v, 4, 64);
                v += __shfl_xor(v, 8, 64);
                pa[i][r] = v;
            }
        if (l16 == 0) {
#pragma unroll
            for (int i = 0; i < 4; i++)
#pragma unroll
                for (int r = 0; r < 4; r++) {
                    int m = m0 + wm + i * 16 + quad * 4 + r;
                    if (MODE == 0) atomicAdd(&probe[b * 512 + m], pa[i][r]);
                    else atomicAdd(&probe[(size_t)(b * 512 + m) * 64 + ((n0 + wn) >> 6)], pa[i][r]);
                }
        }
    } else {
        float* Yb = Y + (size_t)b * DIM * HW;
        float gamma = gammaPtr[0];
        const float* qb = qsrc + (size_t)b * DIM * HW;
#pragma unroll
        for (int j = 0; j < 4; j++) {
            int n = n0 + wn + j * 16 + l16;
            int pix = b * HW + n;
            float mn = mean[pix], rs = rstd[pix];
#pragma unroll
            for (int i = 0; i < 4; i++) {
                int mb = m0 + wm + i * 16 + quad * 4;
#pragma unroll
                for (int r = 0; r < 4; r++) {
                    int m = mb + r;
                    float qn = (qb[(size_t)m * HW + n] - mn) * rs * g[m] + beta[m];
                    Yb[(size_t)m * HW + n] = gamma * acc[i][j][r] + qn;
                }
            }
        }
    }
}

// ---------- kws[row=b*512+I][w] = sum_h |k[b][h*64+w][I]| -------------------
__global__ void kws_kernel(const unsigned short* __restrict__ kbf, float* __restrict__ kws)
{
    int blk = blockIdx.x;     // b*64 + w
    int b = blk >> 6, w = blk & 63;
    int t = threadIdx.x;      // 256, covers I and I+256
    float a0 = 0.f, a1 = 0.f;
    for (int h = 0; h < 64; h++) {
        const unsigned short* row = kbf + (size_t)(b * HW + h * 64 + w) * 512;
        a0 += fabsf(bf2f(row[t]));
        a1 += fabsf(bf2f(row[t + 256]));
    }
    kws[(size_t)(b * 512 + t) * 64 + w] = a0;
    kws[(size_t)(b * 512 + t + 256) * 64 + w] = a1;
}

// ---------- scores + top-8 per bh ------------------------------------------
__global__ void score_topk(const float* __restrict__ qp, const float* __restrict__ khs,
                           const float* __restrict__ kws, int* __restrict__ idx_h, int* __restrict__ idx_w)
{
    int bh = blockIdx.x;
    int lane = threadIdx.x;
    float sr = 0.f, sc = 0.f;
    for (int c = 0; c < 64; c++) {
        float q = qp[bh * 64 + c];
        sr = fmaf(q, khs[(size_t)(bh * 64 + c) * 64 + lane], sr);
        sc = fmaf(q, kws[(size_t)(bh * 64 + c) * 64 + lane], sc);
    }
    float v = sr;
    for (int it = 0; it < 8; it++) {
        float bv = v; int bi = lane;
        for (int off = 1; off < 64; off <<= 1) {
            float ov = __shfl_xor(bv, off, 64);
            int oi = __shfl_xor(bi, off, 64);
            if (ov > bv || (ov == bv && oi < bi)) { bv = ov; bi = oi; }
        }
        if (lane == 0) idx_h[bh * 8 + it] = bi;
        if (lane == bi) v = -INFINITY;
    }
    v = sc;
    for (int it = 0; it < 8; it++) {
        float bv = v; int bi = lane;
        for (int off = 1; off < 64; off <<= 1) {
            float ov = __shfl_xor(bv, off, 64);
            int oi = __shfl_xor(bi, off, 64);
            if (ov > bv || (ov == bv && oi < bi)) { bv = ov; bi = oi; }
        }
        if (lane == 0) idx_w[bh * 8 + it] = bi;
        if (lane == bi) v = -INFINITY;
    }
}

// ---------- gather k rows; compute v at selected pixels ---------------------
// kg: [bh][key][d] bf16, vgt: [bh][d][key] bf16 (attention fragment layouts)
__global__ void gather_kv(const unsigned short* __restrict__ kbf, const unsigned short* __restrict__ ctx_t,
                          const float* __restrict__ wv_g, const float* __restrict__ Av, const float* __restrict__ Cv,
                          const float* __restrict__ ctx_m, const float* __restrict__ ctx_r,
                          const int* __restrict__ idx_h, const int* __restrict__ idx_w,
                          unsigned short* __restrict__ kg, unsigned short* __restrict__ vgt)
{
    int blk = blockIdx.x;    // bh*64 + key
    int bh = blk >> 6, j = blk & 63;
    int h = idx_h[bh * 8 + (j >> 3)];
    int w = idx_w[bh * 8 + (j & 7)];
    int p = h * 64 + w;
    int b = bh >> 3, head = bh & 7;
    int d = threadIdx.x;     // 64
    kg[(size_t)blk * 64 + d] = kbf[(size_t)(b * HW + p) * 512 + head * 64 + d];
    __shared__ float cx[DIM];
    const unsigned short* crow = ctx_t + (size_t)(b * HW + p) * 512;
    short8 cv = ((const short8*)crow)[d];
#pragma unroll
    for (int u = 0; u < 8; u++) cx[d * 8 + u] = bf2f((unsigned short)cv[u]);
    __syncthreads();
    int o = head * 64 + d;
    const float* wrow = wv_g + (size_t)o * DIM;
    float acc = 0.f;
    for (int i = 0; i < DIM; i++) acc = fmaf(wrow[i], cx[i], acc);
    int pix = b * HW + p;
    float v = ctx_r[pix] * (acc - ctx_m[pix] * Av[o]) + Cv[o];
    vgt[((size_t)bh * 64 + d) * 64 + j] = f2bf(v);
}

// ---------- MFMA attention: S^T = K·Q^T, softmax over m, O^T = Vt·P ---------
#define PROW 72  // padded per-query LDS row stride (bf16)
__global__ __launch_bounds__(256) void attn_mfma(
    const unsigned short* __restrict__ qbf, const unsigned short* __restrict__ kg,
    const unsigned short* __restrict__ vgt, unsigned short* __restrict__ abuf)
{
    int bh = blockIdx.y;
    int b = bh >> 3, head = bh & 7;
    int tid = threadIdx.x;
    int lane = tid & 63, wave = tid >> 6;
    int g = lane >> 4, l16 = lane & 15;
    int p0 = blockIdx.x * 256 + wave * 64;

    __shared__ unsigned short Plds[4][64 * PROW];
    unsigned short* P = Plds[wave];

    const unsigned short* kgb = kg + (size_t)bh * 4096;
    const unsigned short* vtb = vgt + (size_t)bh * 4096;
    const unsigned short* qb = qbf + (size_t)(b * HW) * 512 + head * 64;

    short8 Qf[4][2];
#pragma unroll
    for (int j = 0; j < 4; j++)
#pragma unroll
        for (int t = 0; t < 2; t++)
            Qf[j][t] = *(const short8*)(qb + (size_t)(p0 + j * 16 + l16) * 512 + t * 32 + g * 8);

    f32x4 S[4][4];
#pragma unroll
    for (int i = 0; i < 4; i++)
#pragma unroll
        for (int j = 0; j < 4; j++) S[i][j] = (f32x4){0.f, 0.f, 0.f, 0.f};
#pragma unroll
    for (int t = 0; t < 2; t++) {
        short8 Kf[4];
#pragma unroll
        for (int i = 0; i < 4; i++)
            Kf[i] = *(const short8*)(kgb + (i * 16 + l16) * 64 + t * 32 + g * 8);
#pragma unroll
        for (int i = 0; i < 4; i++)
#pragma unroll
            for (int j = 0; j < 4; j++)
                S[i][j] = __builtin_amdgcn_mfma_f32_16x16x32_bf16(Kf[i], Qf[j][t], S[i][j], 0, 0, 0);
    }

    // exp (scores in [-1,1], no max-sub needed), per-query sum, P^T -> LDS [query][key]
    float inv[4];
#pragma unroll
    for (int j = 0; j < 4; j++) {
        float e[4][4];
        float s = 0.f;
#pragma unroll
        for (int i = 0; i < 4; i++)
#pragma unroll
            for (int r = 0; r < 4; r++) { e[i][r] = __expf(S[i][j][r]); s += e[i][r]; }
        s += __shfl_xor(s, 16, 64);
        s += __shfl_xor(s, 32, 64);
        inv[j] = 1.0f / s;
        int row = j * 16 + l16;
#pragma unroll
        for (int i = 0; i < 4; i++) {
            uint2 pk;
            pk.x = pack2(e[i][0], e[i][1]);
            pk.y = pack2(e[i][2], e[i][3]);
            *(uint2*)(P + row * PROW + i * 16 + g * 4) = pk;
        }
    }

    f32x4 O[4][4];
#pragma unroll
    for (int i = 0; i < 4; i++)
#pragma unroll
        for (int j = 0; j < 4; j++) O[i][j] = (f32x4){0.f, 0.f, 0.f, 0.f};
#pragma unroll
    for (int t = 0; t < 2; t++) {
        short8 Vf[4], Pf[4];
#pragma unroll
        for (int i = 0; i < 4; i++)
            Vf[i] = *(const short8*)(vtb + (i * 16 + l16) * 64 + t * 32 + g * 8);
#pragma unroll
        for (int j = 0; j < 4; j++)
            Pf[j] = *(const short8*)(P + (j * 16 + l16) * PROW + t * 32 + g * 8);
#pragma unroll
        for (int i = 0; i < 4; i++)
#pragma unroll
            for (int j = 0; j < 4; j++)
                O[i][j] = __builtin_amdgcn_mfma_f32_16x16x32_bf16(Vf[i], Pf[j], O[i][j], 0, 0, 0);
    }

    unsigned short* ob = abuf + (size_t)(b * HW) * 512 + head * 64;
#pragma unroll
    for (int j = 0; j < 4; j++) {
        int p = p0 + j * 16 + l16;
#pragma unroll
        for (int i = 0; i < 4; i++) {
            uint2 pk;
            pk.x = pack2(O[i][j][0] * inv[j], O[i][j][1] * inv[j]);
            pk.y = pack2(O[i][j][2] * inv[j], O[i][j][3] * inv[j]);
            *(uint2*)(ob + (size_t)p * 512 + i * 16 + g * 4) = pk;
        }
    }
}

extern "C" void kernel_launch(void* const* d_in, const int* in_sizes, int n_in,
                              void* d_out, int out_size, void* d_ws, size_t ws_size,
                              hipStream_t stream)
{
    (void)in_sizes; (void)n_in; (void)out_size; (void)ws_size;
    const float* ctx   = (const float*)d_in[0];
    const float* qs    = (const float*)d_in[1];
    const float* ctx_g = (const float*)d_in[2];
    const float* ctx_b = (const float*)d_in[3];
    const float* qs_g  = (const float*)d_in[4];
    const float* qs_b  = (const float*)d_in[5];
    const float* w_q   = (const float*)d_in[6];
    const float* w_kv  = (const float*)d_in[7];
    const float* w_out = (const float*)d_in[8];
    const float* gamma = (const float*)d_in[9];
    float* out = (float*)d_out;

    char* base = (char*)d_ws;
    // [0,32M): ctx_t bf16; aliased by abuf after gather (attn output)
    // [32M,64M): qs_t bf16; aliased by kbf bf16 after q-GEMM
    // [64M,96M): qbf bf16
    // [96M,..): small buffers
    unsigned short* ctx_t = (unsigned short*)base;
    unsigned short* abuf  = ctx_t;
    unsigned short* qs_t  = (unsigned short*)(base + ((size_t)32 << 20));
    unsigned short* kbf   = qs_t;
    unsigned short* qbf   = (unsigned short*)(base + ((size_t)64 << 20));
    char* tail = base + ((size_t)96 << 20);
    unsigned short* wq_b = (unsigned short*)tail;            // 262144 elems
    unsigned short* wk_b = wq_b + 262144;
    unsigned short* wo_b = wk_b + 262144;
    float* wv_g  = (float*)(wo_b + 262144);                  // 262144 f
    float* Avec  = wv_g + 262144;                            // 1536
    float* Cvec  = Avec + 1536;
    float* ctx_m = Cvec + 1536;                              // 32768 each
    float* ctx_r = ctx_m + 32768;
    float* qs_m  = ctx_r + 32768;
    float* qs_r  = qs_m + 32768;
    float* qp    = qs_r + 32768;                             // 4096
    float* khs   = qp + 4096;                                // 262144
    float* kws   = khs + 262144;                             // 262144
    int*   idxh  = (int*)(kws + 262144);                     // 512
    int*   idxw  = idxh + 512;
    unsigned short* kg  = (unsigned short*)(idxw + 512);     // 262144 bf16
    unsigned short* vgt = kg + 262144;                       // 262144 bf16

    hipMemsetAsync(qp, 0, 4096 * sizeof(float), stream);
    hipMemsetAsync(khs, 0, 262144 * sizeof(float), stream);

    prep_weights<<<2048, 256, 0, stream>>>(w_q, w_kv, w_out, ctx_g, ctx_b, qs_g, qs_b,
                                           wq_b, wk_b, wo_b, wv_g, Avec, Cvec);
    conv_stats<<<dim3(64, 8, 2), 256, 0, stream>>>(ctx, qs, ctx_t, qs_t,
                                                   ctx_m, ctx_r, qs_m, qs_r);
    gemm_mfma<0><<<dim3(32, 4, 8), 256, 0, stream>>>(wq_b, qs_t, nullptr, qbf, qs_m, qs_r,
                                                     Avec, Cvec, qp, nullptr, nullptr, nullptr, nullptr);
    gemm_mfma<1><<<dim3(32, 4, 8), 256, 0, stream>>>(wk_b, ctx_t, nullptr, kbf, ctx_m, ctx_r,
                                                     Avec + 512, Cvec + 512, khs, nullptr, nullptr, nullptr, nullptr);
    kws_kernel<<<512, 256, 0, stream>>>(kbf, kws);
    score_topk<<<64, 64, 0, stream>>>(qp, khs, kws, idxh, idxw);
    gather_kv<<<4096, 64, 0, stream>>>(kbf, ctx_t, wv_g, Avec + 1024, Cvec + 1024,
                                       ctx_m, ctx_r, idxh, idxw, kg, vgt);
    attn_mfma<<<dim3(16, 64), 256, 0, stream>>>(qbf, kg, vgt, abuf);
    gemm_mfma<2><<<dim3(32, 4, 8), 256, 0, stream>>>(wo_b, abuf, out, nullptr, qs_m, qs_r,
                                                     nullptr, nullptr, nullptr, qs, qs_g, qs_b, gamma);
}

// Round 4
// 449.599 us; speedup vs baseline: 2.9359x; 1.0702x over previous
//
#include <hip/hip_runtime.h>
#include <math.h>

#define HW 4096
#define DIM 512

typedef __attribute__((ext_vector_type(8))) short short8;
typedef __attribute__((ext_vector_type(4))) float f32x4;

__device__ inline unsigned short f2bf(float f) {
    unsigned int u = __float_as_uint(f);
    u += 0x7fff + ((u >> 16) & 1);   // round-to-nearest-even
    return (unsigned short)(u >> 16);
}
__device__ inline float bf2f(unsigned short h) {
    return __uint_as_float(((unsigned int)h) << 16);
}
__device__ inline unsigned pack2(float a, float b) {
    return (unsigned)f2bf(a) | ((unsigned)f2bf(b) << 16);
}

// async global->LDS, 16 B per lane. LDS dest = wave-uniform base + lane*16.
__device__ inline void gld16(const void* g, void* lds) {
    __builtin_amdgcn_global_load_lds(
        (const __attribute__((address_space(1))) unsigned int*)g,
        (__attribute__((address_space(3))) unsigned int*)lds, 16, 0, 0);
}

// ---------- prep weights: bf16 w*g for q/k, fp32 w*g for v, bf16 w_out ------
__global__ void prep_weights(const float* __restrict__ w_q, const float* __restrict__ w_kv,
                             const float* __restrict__ w_out,
                             const float* __restrict__ ctx_g, const float* __restrict__ ctx_b,
                             const float* __restrict__ qs_g, const float* __restrict__ qs_b,
                             unsigned short* __restrict__ wq_b, unsigned short* __restrict__ wk_b,
                             unsigned short* __restrict__ wo_b, float* __restrict__ wv_g,
                             float* __restrict__ Avec, float* __restrict__ Cvec)
{
    int blk = blockIdx.x;
    int widx = blk >> 9;
    int o = blk & 511;
    int tid = threadIdx.x;
    const float *src, *g = nullptr, *beta = nullptr;
    if (widx == 0)      { src = w_q  + (size_t)o * DIM; g = qs_g;  beta = qs_b; }
    else if (widx == 1) { src = w_kv + (size_t)o * DIM; g = ctx_g; beta = ctx_b; }
    else if (widx == 2) { src = w_kv + (size_t)(512 + o) * DIM; g = ctx_g; beta = ctx_b; }
    else                { src = w_out + (size_t)o * DIM; }
    float a = 0.f, c = 0.f;
    for (int i = tid; i < DIM; i += 256) {
        float w = src[i];
        if (widx == 3) { wo_b[(size_t)o * DIM + i] = f2bf(w); continue; }
        float wg = w * g[i];
        if (widx == 0)      wq_b[(size_t)o * DIM + i] = f2bf(wg);
        else if (widx == 1) wk_b[(size_t)o * DIM + i] = f2bf(wg);
        else                wv_g[(size_t)o * DIM + i] = wg;
        a += wg; c += w * beta[i];
    }
    if (widx == 3) return;  // uniform across block
    __shared__ float sa[256], sc[256];
    sa[tid] = a; sc[tid] = c;
    __syncthreads();
    for (int s = 128; s > 0; s >>= 1) {
        if (tid < s) { sa[tid] += sa[tid + s]; sc[tid] += sc[tid + s]; }
        __syncthreads();
    }
    if (tid == 0) { Avec[widx * 512 + o] = sa[0]; Cvec[widx * 512 + o] = sc[0]; }
}

// ---------- fused fp32->bf16 transpose + chan stats, LDS-staged -------------
// Block: 64 pixels x 512 channels. 2 channel-chunks of 256 (32 KB LDS tile).
// Phase A: coalesced reads (lane=pixel), pack 8-ch uint4, swizzled LDS write.
// Phase B: thread owns (pixel, c2) and writes so each 64B line completes in
// one instruction (lanes 0-3 cover 64 consecutive bytes).
__global__ __launch_bounds__(256) void conv_stats(
    const float* __restrict__ ctx, const float* __restrict__ qs,
    unsigned short* __restrict__ ctx_t, unsigned short* __restrict__ qs_t,
    float* __restrict__ ctx_m, float* __restrict__ ctx_r,
    float* __restrict__ qs_m, float* __restrict__ qs_r)
{
    int which = blockIdx.z;
    int b = blockIdx.y;
    int p0 = blockIdx.x * 64;
    const float* X = (which ? qs : ctx) + (size_t)b * DIM * HW;
    unsigned short* Xt = (which ? qs_t : ctx_t) + (size_t)b * HW * DIM;
    int tid = threadIdx.x;
    int p = tid & 63;          // pixel within tile (Phase A)
    int q4 = tid >> 6;         // wave = channel slice
    const float* col = X + p0 + p;

    __shared__ uint4 tile[64 * 32];      // 32 KB: [pixel][cg^(p&15)]
    __shared__ float sbuf[256], ssbuf[256];

    float s = 0.f, ss = 0.f;
    for (int chunk = 0; chunk < 2; chunk++) {
        for (int si = 0; si < 8; si++) {
            int cgl = q4 * 8 + si;               // 0..31 within chunk
            int c = chunk * 256 + cgl * 8;
            float v[8];
#pragma unroll
            for (int j = 0; j < 8; j++) {
                v[j] = col[(size_t)(c + j) * HW];
                s += v[j]; ss = fmaf(v[j], v[j], ss);
            }
            uint4 pk;
            pk.x = pack2(v[0], v[1]);
            pk.y = pack2(v[2], v[3]);
            pk.z = pack2(v[4], v[5]);
            pk.w = pack2(v[6], v[7]);
            tile[p * 32 + (cgl ^ (p & 15))] = pk;
        }
        __syncthreads();
        // Phase B: pr = tid>>2, c2 = tid&3 -> lanes 0-3 write 64B lines whole
        int pr = tid >> 2, c2 = tid & 3;
        unsigned short* orow = Xt + (size_t)(p0 + pr) * 512 + chunk * 256;
#pragma unroll
        for (int si = 0; si < 8; si++) {
            int cgl = c2 + si * 4;
            uint4 d = tile[pr * 32 + (cgl ^ (pr & 15))];
            *(uint4*)(orow + cgl * 8) = d;
        }
        __syncthreads();
    }

    sbuf[tid] = s; ssbuf[tid] = ss;
    __syncthreads();
    if (tid < 64) {
        float st  = sbuf[tid] + sbuf[tid + 64] + sbuf[tid + 128] + sbuf[tid + 192];
        float sst = ssbuf[tid] + ssbuf[tid + 64] + ssbuf[tid + 128] + ssbuf[tid + 192];
        float m = st * (1.0f / DIM);
        float var = sst * (1.0f / DIM) - m * m;
        float r = 1.0f / sqrtf(var + 1e-5f);
        int pix = b * HW + p0 + tid;
        if (which == 0) { ctx_m[pix] = m; ctx_r[pix] = r; }
        else            { qs_m[pix]  = m; qs_r[pix]  = r; }
    }
}

// ---------- bf16 MFMA GEMM, 128x128 tile, global_load_lds staging -----------
// MODE 0: q proj -> l2norm -> bf16 [p][512]; |.| row sums atomics into probe[b*512+m]
// MODE 1: k proj -> l2norm -> bf16 [p][512]; khs atomics into probe[(b*512+m)*64+h]
// MODE 2: out GEMM -> fp32 [m][p] with gamma*acc + LN(qsrc) residual
template<int MODE>
__global__ __launch_bounds__(256) void gemm_mfma(
    const unsigned short* __restrict__ Wb, const unsigned short* __restrict__ Xt,
    float* __restrict__ Y, unsigned short* __restrict__ Ybf,
    const float* __restrict__ mean, const float* __restrict__ rstd,
    const float* __restrict__ Arow, const float* __restrict__ Crow,
    float* __restrict__ probe,
    const float* __restrict__ qsrc, const float* __restrict__ g,
    const float* __restrict__ beta, const float* __restrict__ gammaPtr)
{
    int b = blockIdx.z;
    int n0 = blockIdx.x * 128;
    int m0 = blockIdx.y * 128;
    const unsigned short* Xb = Xt + (size_t)b * HW * DIM;
    __shared__ uint4 AsBuf[512];   // 128 rows (m) x 32 k bf16
    __shared__ uint4 BsBuf[512];   // 128 rows (n) x 32 k bf16
    unsigned short* As = (unsigned short*)AsBuf;
    unsigned short* Bs = (unsigned short*)BsBuf;
    int tid = threadIdx.x;
    int lane = tid & 63;
    int wave = tid >> 6;
    int wbase = tid & 192;         // wave*64 (wave-uniform)
    int wm = (wave >> 1) * 64;
    int wn = (wave & 1) * 64;
    int quad = lane >> 4;
    int l16 = lane & 15;

    int r0 = tid >> 2, c0 = (tid & 3) * 8;
    const unsigned short* pA0 = Wb + (size_t)(m0 + r0) * DIM + c0;
    const unsigned short* pA1 = Wb + (size_t)(m0 + 64 + r0) * DIM + c0;
    const unsigned short* pB0 = Xb + (size_t)(n0 + r0) * DIM + c0;
    const unsigned short* pB1 = Xb + (size_t)(n0 + 64 + r0) * DIM + c0;

    f32x4 acc[4][4];
#pragma unroll
    for (int i = 0; i < 4; i++)
#pragma unroll
        for (int j = 0; j < 4; j++) acc[i][j] = (f32x4){0.f, 0.f, 0.f, 0.f};

    for (int kt = 0; kt < 16; kt++) {
        gld16(pA0, AsBuf + wbase);
        gld16(pA1, AsBuf + 256 + wbase);
        gld16(pB0, BsBuf + wbase);
        gld16(pB1, BsBuf + 256 + wbase);
        pA0 += 32; pA1 += 32; pB0 += 32; pB1 += 32;
        __syncthreads();   // drains vmcnt -> staged data visible
        short8 af[4], bfr[4];
#pragma unroll
        for (int i = 0; i < 4; i++)
            af[i] = *(const short8*)(As + (wm + i * 16 + l16) * 32 + quad * 8);
#pragma unroll
        for (int j = 0; j < 4; j++)
            bfr[j] = *(const short8*)(Bs + (wn + j * 16 + l16) * 32 + quad * 8);
#pragma unroll
        for (int i = 0; i < 4; i++)
#pragma unroll
            for (int j = 0; j < 4; j++)
                acc[i][j] = __builtin_amdgcn_mfma_f32_16x16x32_bf16(af[i], bfr[j], acc[i][j], 0, 0, 0);
        __syncthreads();
    }

    if (MODE < 2) {
        float pa[4][4] = {};
#pragma unroll
        for (int j = 0; j < 4; j++) {
            int n = n0 + wn + j * 16 + l16;
            int pix = b * HW + n;
            float mn = mean[pix], rs = rstd[pix];
            float y[4][4];
            float s2 = 0.f;
#pragma unroll
            for (int i = 0; i < 4; i++) {
                int mb = m0 + wm + i * 16 + quad * 4;
#pragma unroll
                for (int r = 0; r < 4; r++) {
                    float v = rs * (acc[i][j][r] - mn * Arow[mb + r]) + Crow[mb + r];
                    y[i][r] = v;
                    s2 = fmaf(v, v, s2);
                }
            }
            // head l2-norm: wave spans exactly one 64-channel head in m
            s2 += __shfl_xor(s2, 16, 64);
            s2 += __shfl_xor(s2, 32, 64);
            float inv = 1.0f / fmaxf(sqrtf(s2), 1e-12f);
            unsigned short* orow = Ybf + (size_t)(b * HW + n) * 512 + m0 + wm + quad * 4;
#pragma unroll
            for (int i = 0; i < 4; i++) {
                float v0 = y[i][0] * inv, v1 = y[i][1] * inv;
                float v2 = y[i][2] * inv, v3 = y[i][3] * inv;
                uint2 pk; pk.x = pack2(v0, v1); pk.y = pack2(v2, v3);
                *(uint2*)(orow + i * 16) = pk;
                pa[i][0] += fabsf(v0); pa[i][1] += fabsf(v1);
                pa[i][2] += fabsf(v2); pa[i][3] += fabsf(v3);
            }
        }
#pragma unroll
        for (int i = 0; i < 4; i++)
#pragma unroll
            for (int r = 0; r < 4; r++) {
                float v = pa[i][r];
                v += __shfl_xor(v, 1, 64);
                v += __shfl_xor(v, 2, 64);
                v += __shfl_xor(v, 4, 64);
                v += __shfl_xor(v, 8, 64);
                pa[i][r] = v;
            }
        if (l16 == 0) {
#pragma unroll
            for (int i = 0; i < 4; i++)
#pragma unroll
                for (int r = 0; r < 4; r++) {
                    int m = m0 + wm + i * 16 + quad * 4 + r;
                    if (MODE == 0) atomicAdd(&probe[b * 512 + m], pa[i][r]);
                    else atomicAdd(&probe[(size_t)(b * 512 + m) * 64 + ((n0 + wn) >> 6)], pa[i][r]);
                }
        }
    } else {
        float* Yb = Y + (size_t)b * DIM * HW;
        float gamma = gammaPtr[0];
        const float* qb = qsrc + (size_t)b * DIM * HW;
#pragma unroll
        for (int j = 0; j < 4; j++) {
            int n = n0 + wn + j * 16 + l16;
            int pix = b * HW + n;
            float mn = mean[pix], rs = rstd[pix];
#pragma unroll
            for (int i = 0; i < 4; i++) {
                int mb = m0 + wm + i * 16 + quad * 4;
#pragma unroll
                for (int r = 0; r < 4; r++) {
                    int m = mb + r;
                    float qn = (qb[(size_t)m * HW + n] - mn) * rs * g[m] + beta[m];
                    Yb[(size_t)m * HW + n] = gamma * acc[i][j][r] + qn;
                }
            }
        }
    }
}

// ---------- kws[(b*512+c)][w] = sum_h |k[b][h*64+w][c]|, vectorized ---------
__global__ __launch_bounds__(256) void kws_kernel(const unsigned short* __restrict__ kbf,
                                                  float* __restrict__ kws)
{
    int blk = blockIdx.x;     // b*64 + w
    int b = blk >> 6, w = blk & 63;
    int tid = threadIdx.x;
    int c8 = tid & 63;        // channel group of 8
    int hq = tid >> 6;        // 4 h-slices of 16
    float a[8] = {};
    for (int hh = 0; hh < 16; hh++) {
        const unsigned short* row = kbf + ((size_t)(b * HW + (hq * 16 + hh) * 64 + w)) * 512 + c8 * 8;
        uint4 pk = *(const uint4*)row;
        const unsigned short* u = (const unsigned short*)&pk;
#pragma unroll
        for (int j = 0; j < 8; j++) a[j] += fabsf(bf2f(u[j]));
    }
    __shared__ float red[512 * 4];
#pragma unroll
    for (int j = 0; j < 8; j++) red[(c8 * 8 + j) * 4 + hq] = a[j];
    __syncthreads();
    if (tid < 256) {
        int c = tid;
        float v0 = red[c * 4] + red[c * 4 + 1] + red[c * 4 + 2] + red[c * 4 + 3];
        int c2 = tid + 256;
        float v1 = red[c2 * 4] + red[c2 * 4 + 1] + red[c2 * 4 + 2] + red[c2 * 4 + 3];
        kws[(size_t)(b * 512 + c) * 64 + w] = v0;
        kws[(size_t)(b * 512 + c2) * 64 + w] = v1;
    }
}

// ---------- scores + top-8 per bh ------------------------------------------
__global__ void score_topk(const float* __restrict__ qp, const float* __restrict__ khs,
                           const float* __restrict__ kws, int* __restrict__ idx_h, int* __restrict__ idx_w)
{
    int bh = blockIdx.x;
    int lane = threadIdx.x;
    float sr = 0.f, sc = 0.f;
    for (int c = 0; c < 64; c++) {
        float q = qp[bh * 64 + c];
        sr = fmaf(q, khs[(size_t)(bh * 64 + c) * 64 + lane], sr);
        sc = fmaf(q, kws[(size_t)(bh * 64 + c) * 64 + lane], sc);
    }
    float v = sr;
    for (int it = 0; it < 8; it++) {
        float bv = v; int bi = lane;
        for (int off = 1; off < 64; off <<= 1) {
            float ov = __shfl_xor(bv, off, 64);
            int oi = __shfl_xor(bi, off, 64);
            if (ov > bv || (ov == bv && oi < bi)) { bv = ov; bi = oi; }
        }
        if (lane == 0) idx_h[bh * 8 + it] = bi;
        if (lane == bi) v = -INFINITY;
    }
    v = sc;
    for (int it = 0; it < 8; it++) {
        float bv = v; int bi = lane;
        for (int off = 1; off < 64; off <<= 1) {
            float ov = __shfl_xor(bv, off, 64);
            int oi = __shfl_xor(bi, off, 64);
            if (ov > bv || (ov == bv && oi < bi)) { bv = ov; bi = oi; }
        }
        if (lane == 0) idx_w[bh * 8 + it] = bi;
        if (lane == bi) v = -INFINITY;
    }
}

// ---------- gather k rows; compute v at selected pixels ---------------------
__global__ void gather_kv(const unsigned short* __restrict__ kbf, const unsigned short* __restrict__ ctx_t,
                          const float* __restrict__ wv_g, const float* __restrict__ Av, const float* __restrict__ Cv,
                          const float* __restrict__ ctx_m, const float* __restrict__ ctx_r,
                          const int* __restrict__ idx_h, const int* __restrict__ idx_w,
                          unsigned short* __restrict__ kg, unsigned short* __restrict__ vgt)
{
    int blk = blockIdx.x;    // bh*64 + key
    int bh = blk >> 6, j = blk & 63;
    int h = idx_h[bh * 8 + (j >> 3)];
    int w = idx_w[bh * 8 + (j & 7)];
    int p = h * 64 + w;
    int b = bh >> 3, head = bh & 7;
    int d = threadIdx.x;     // 64
    kg[(size_t)blk * 64 + d] = kbf[(size_t)(b * HW + p) * 512 + head * 64 + d];
    __shared__ float cx[DIM];
    const unsigned short* crow = ctx_t + (size_t)(b * HW + p) * 512;
    short8 cv = ((const short8*)crow)[d];
#pragma unroll
    for (int u = 0; u < 8; u++) cx[d * 8 + u] = bf2f((unsigned short)cv[u]);
    __syncthreads();
    int o = head * 64 + d;
    const float* wrow = wv_g + (size_t)o * DIM;
    float acc = 0.f;
    for (int i = 0; i < DIM; i++) acc = fmaf(wrow[i], cx[i], acc);
    int pix = b * HW + p;
    float v = ctx_r[pix] * (acc - ctx_m[pix] * Av[o]) + Cv[o];
    vgt[((size_t)bh * 64 + d) * 64 + j] = f2bf(v);
}

// ---------- MFMA attention: S^T = K·Q^T, softmax over m, O^T = Vt·P ---------
#define PROW 72  // padded per-query LDS row stride (bf16)
__global__ __launch_bounds__(256) void attn_mfma(
    const unsigned short* __restrict__ qbf, const unsigned short* __restrict__ kg,
    const unsigned short* __restrict__ vgt, unsigned short* __restrict__ abuf)
{
    int bh = blockIdx.y;
    int b = bh >> 3, head = bh & 7;
    int tid = threadIdx.x;
    int lane = tid & 63, wave = tid >> 6;
    int g = lane >> 4, l16 = lane & 15;
    int p0 = blockIdx.x * 256 + wave * 64;

    __shared__ unsigned short Plds[4][64 * PROW];
    unsigned short* P = Plds[wave];

    const unsigned short* kgb = kg + (size_t)bh * 4096;
    const unsigned short* vtb = vgt + (size_t)bh * 4096;
    const unsigned short* qb = qbf + (size_t)(b * HW) * 512 + head * 64;

    short8 Qf[4][2];
#pragma unroll
    for (int j = 0; j < 4; j++)
#pragma unroll
        for (int t = 0; t < 2; t++)
            Qf[j][t] = *(const short8*)(qb + (size_t)(p0 + j * 16 + l16) * 512 + t * 32 + g * 8);

    f32x4 S[4][4];
#pragma unroll
    for (int i = 0; i < 4; i++)
#pragma unroll
        for (int j = 0; j < 4; j++) S[i][j] = (f32x4){0.f, 0.f, 0.f, 0.f};
#pragma unroll
    for (int t = 0; t < 2; t++) {
        short8 Kf[4];
#pragma unroll
        for (int i = 0; i < 4; i++)
            Kf[i] = *(const short8*)(kgb + (i * 16 + l16) * 64 + t * 32 + g * 8);
#pragma unroll
        for (int i = 0; i < 4; i++)
#pragma unroll
            for (int j = 0; j < 4; j++)
                S[i][j] = __builtin_amdgcn_mfma_f32_16x16x32_bf16(Kf[i], Qf[j][t], S[i][j], 0, 0, 0);
    }

    float inv[4];
#pragma unroll
    for (int j = 0; j < 4; j++) {
        float e[4][4];
        float s = 0.f;
#pragma unroll
        for (int i = 0; i < 4; i++)
#pragma unroll
            for (int r = 0; r < 4; r++) { e[i][r] = __expf(S[i][j][r]); s += e[i][r]; }
        s += __shfl_xor(s, 16, 64);
        s += __shfl_xor(s, 32, 64);
        inv[j] = 1.0f / s;
        int row = j * 16 + l16;
#pragma unroll
        for (int i = 0; i < 4; i++) {
            uint2 pk;
            pk.x = pack2(e[i][0], e[i][1]);
            pk.y = pack2(e[i][2], e[i][3]);
            *(uint2*)(P + row * PROW + i * 16 + g * 4) = pk;
        }
    }

    f32x4 O[4][4];
#pragma unroll
    for (int i = 0; i < 4; i++)
#pragma unroll
        for (int j = 0; j < 4; j++) O[i][j] = (f32x4){0.f, 0.f, 0.f, 0.f};
#pragma unroll
    for (int t = 0; t < 2; t++) {
        short8 Vf[4], Pf[4];
#pragma unroll
        for (int i = 0; i < 4; i++)
            Vf[i] = *(const short8*)(vtb + (i * 16 + l16) * 64 + t * 32 + g * 8);
#pragma unroll
        for (int j = 0; j < 4; j++)
            Pf[j] = *(const short8*)(P + (j * 16 + l16) * PROW + t * 32 + g * 8);
#pragma unroll
        for (int i = 0; i < 4; i++)
#pragma unroll
            for (int j = 0; j < 4; j++)
                O[i][j] = __builtin_amdgcn_mfma_f32_16x16x32_bf16(Vf[i], Pf[j], O[i][j], 0, 0, 0);
    }

    unsigned short* ob = abuf + (size_t)(b * HW) * 512 + head * 64;
#pragma unroll
    for (int j = 0; j < 4; j++) {
        int p = p0 + j * 16 + l16;
#pragma unroll
        for (int i = 0; i < 4; i++) {
            uint2 pk;
            pk.x = pack2(O[i][j][0] * inv[j], O[i][j][1] * inv[j]);
            pk.y = pack2(O[i][j][2] * inv[j], O[i][j][3] * inv[j]);
            *(uint2*)(ob + (size_t)p * 512 + i * 16 + g * 4) = pk;
        }
    }
}

extern "C" void kernel_launch(void* const* d_in, const int* in_sizes, int n_in,
                              void* d_out, int out_size, void* d_ws, size_t ws_size,
                              hipStream_t stream)
{
    (void)in_sizes; (void)n_in; (void)out_size; (void)ws_size;
    const float* ctx   = (const float*)d_in[0];
    const float* qs    = (const float*)d_in[1];
    const float* ctx_g = (const float*)d_in[2];
    const float* ctx_b = (const float*)d_in[3];
    const float* qs_g  = (const float*)d_in[4];
    const float* qs_b  = (const float*)d_in[5];
    const float* w_q   = (const float*)d_in[6];
    const float* w_kv  = (const float*)d_in[7];
    const float* w_out = (const float*)d_in[8];
    const float* gamma = (const float*)d_in[9];
    float* out = (float*)d_out;

    char* base = (char*)d_ws;
    unsigned short* ctx_t = (unsigned short*)base;                 // 32 MB
    unsigned short* abuf  = ctx_t;                                 // alias after gather
    unsigned short* qs_t  = (unsigned short*)(base + ((size_t)32 << 20));
    unsigned short* kbf   = qs_t;                                  // alias after q-GEMM... (qs_t dead post k-GEMM staging read)
    unsigned short* qbf   = (unsigned short*)(base + ((size_t)64 << 20));
    char* tail = base + ((size_t)96 << 20);
    unsigned short* wq_b = (unsigned short*)tail;                  // 262144 elems
    unsigned short* wk_b = wq_b + 262144;
    unsigned short* wo_b = wk_b + 262144;
    float* wv_g  = (float*)(wo_b + 262144);                        // 262144 f
    float* Avec  = wv_g + 262144;                                  // 1536
    float* Cvec  = Avec + 1536;
    float* ctx_m = Cvec + 1536;                                    // 32768 each
    float* ctx_r = ctx_m + 32768;
    float* qs_m  = ctx_r + 32768;
    float* qs_r  = qs_m + 32768;
    float* qp    = qs_r + 32768;                                   // 4096
    float* khs   = qp + 4096;                                      // 262144
    float* kws   = khs + 262144;                                   // 262144
    int*   idxh  = (int*)(kws + 262144);                           // 512
    int*   idxw  = idxh + 512;
    unsigned short* kg  = (unsigned short*)(idxw + 512);           // 262144 bf16
    unsigned short* vgt = kg + 262144;                             // 262144 bf16

    hipMemsetAsync(qp, 0, 4096 * sizeof(float), stream);
    hipMemsetAsync(khs, 0, 262144 * sizeof(float), stream);

    prep_weights<<<2048, 256, 0, stream>>>(w_q, w_kv, w_out, ctx_g, ctx_b, qs_g, qs_b,
                                           wq_b, wk_b, wo_b, wv_g, Avec, Cvec);
    conv_stats<<<dim3(64, 8, 2), 256, 0, stream>>>(ctx, qs, ctx_t, qs_t,
                                                   ctx_m, ctx_r, qs_m, qs_r);
    gemm_mfma<0><<<dim3(32, 4, 8), 256, 0, stream>>>(wq_b, qs_t, nullptr, qbf, qs_m, qs_r,
                                                     Avec, Cvec, qp, nullptr, nullptr, nullptr, nullptr);
    gemm_mfma<1><<<dim3(32, 4, 8), 256, 0, stream>>>(wk_b, ctx_t, nullptr, kbf, ctx_m, ctx_r,
                                                     Avec + 512, Cvec + 512, khs, nullptr, nullptr, nullptr, nullptr);
    kws_kernel<<<512, 256, 0, stream>>>(kbf, kws);
    score_topk<<<64, 64, 0, stream>>>(qp, khs, kws, idxh, idxw);
    gather_kv<<<4096, 64, 0, stream>>>(kbf, ctx_t, wv_g, Avec + 1024, Cvec + 1024,
                                       ctx_m, ctx_r, idxh, idxw, kg, vgt);
    attn_mfma<<<dim3(16, 64), 256, 0, stream>>>(qbf, kg, vgt, abuf);
    gemm_mfma<2><<<dim3(32, 4, 8), 256, 0, stream>>>(wo_b, abuf, out, nullptr, qs_m, qs_r,
                                                     nullptr, nullptr, nullptr, qs, qs_g, qs_b, gamma);
}